// Round 3
// baseline (200.208 us; speedup 1.0000x reference)
//
#include <hip/hip_runtime.h>

#define BB   32
#define SS   100
#define TT   4
#define NCC2 500
#define NC3P 2001
#define DD   128

// LDS float-index layout
//  GRU : h[0..127] | part[128..895] | presum[896..3199] | gam[3200..3299] | rr[3300..3399] | h_all[3456..16255]
//  scan: C2s[0..499] | C3s[500..2500] | tc2[2501..2600] | tc3[2604..3003](16B-aligned) | tgam[3004..3103] | trr[3104..3203]
#define HALL 3456
#define LDSF 16256

__device__ __forceinline__ float fast_rcp(float x) { return __builtin_amdgcn_rcpf(x); }
__device__ __forceinline__ float fast_sig(float x) { return fast_rcp(1.f + __expf(-x)); }
__device__ __forceinline__ float fast_tanh(float x) { return 1.f - 2.f * fast_rcp(__expf(2.f * x) + 1.f); }

// Full 64-lane sum via DPP; result valid in lane 63 only.
__device__ __forceinline__ float dpp_sum64(float x) {
    x += __int_as_float(__builtin_amdgcn_update_dpp(0, __float_as_int(x), 0x111, 0xf, 0xf, true)); // row_shr:1
    x += __int_as_float(__builtin_amdgcn_update_dpp(0, __float_as_int(x), 0x112, 0xf, 0xf, true)); // row_shr:2
    x += __int_as_float(__builtin_amdgcn_update_dpp(0, __float_as_int(x), 0x114, 0xf, 0xf, true)); // row_shr:4
    x += __int_as_float(__builtin_amdgcn_update_dpp(0, __float_as_int(x), 0x118, 0xf, 0xf, true)); // row_shr:8
    x += __int_as_float(__builtin_amdgcn_update_dpp(0, __float_as_int(x), 0x142, 0xa, 0xf, true)); // row_bcast:15
    x += __int_as_float(__builtin_amdgcn_update_dpp(0, __float_as_int(x), 0x143, 0xc, 0xf, true)); // row_bcast:31
    return x;
}

__device__ __forceinline__ float dot128(const float* __restrict__ w, const float* __restrict__ v) {
    float s0 = 0.f, s1 = 0.f, s2 = 0.f, s3 = 0.f;
#pragma unroll
    for (int k = 0; k < 128; k += 4) {
        float4 a = *reinterpret_cast<const float4*>(w + k);
        float4 b = *reinterpret_cast<const float4*>(v + k);
        s0 = fmaf(a.x, b.x, s0); s1 = fmaf(a.y, b.y, s1);
        s2 = fmaf(a.z, b.z, s2); s3 = fmaf(a.w, b.w, s3);
    }
    return (s0 + s1) + (s2 + s3);
}

#define FMA4(W, H) do { a0 = fmaf((W).x, (H).x, a0); a1 = fmaf((W).y, (H).y, a1); \
                        a2 = fmaf((W).z, (H).z, a2); a3 = fmaf((W).w, (H).w, a3); } while (0)

// ---------------------------------------------------------------------------
// blocks 0..31 : GRU (768 thr, k-split x2, W_hh in named VGPRs, LDS-only loop)
//                + post-loop h_out writeback + fused alpha MLP
// blocks 32..63: scan (1 wave, barrier-free, reg-resident u-vectors,
//                DPP reductions, fused snapshot stores)
__global__ __launch_bounds__(768, 1) void k_main(
    const int* __restrict__ c2_seq, const int* __restrict__ c3_seq,
    const int* __restrict__ d_seq,  const int* __restrict__ r_seq,
    const float* __restrict__ D_emb, const float* __restrict__ Remb,
    const float* __restrict__ v_c2, const float* __restrict__ v_c3,
    const float* __restrict__ v_d,
    const float* __restrict__ W_ih, const float* __restrict__ W_hh,
    const float* __restrict__ b_ih, const float* __restrict__ b_hh,
    const float* __restrict__ l1W1, const float* __restrict__ l1b1,
    const float* __restrict__ l1W2, const float* __restrict__ l1b2,
    const float* __restrict__ l2W1, const float* __restrict__ l2b1,
    const float* __restrict__ l2W2, const float* __restrict__ l2b2,
    const float* __restrict__ l3W1, const float* __restrict__ l3b1,
    const float* __restrict__ l3W2, const float* __restrict__ l3b2,
    float* __restrict__ alpha, float* __restrict__ h_out,
    float* __restrict__ C2o, float* __restrict__ C3o)
{
    __shared__ __align__(16) float sh[LDSF];
    int* shi = (int*)sh;
    const int blk = blockIdx.x;
    const int t = threadIdx.x;

    if (blk < BB) {
        // =============== GRU role ===============
        const int b = blk;
        const int p = (t >= 384) ? 1 : 0;
        const int j = t - p * 384;
        const float4* wrow = reinterpret_cast<const float4*>(W_hh + j * DD + p * 64);
        // named SSA values -> guaranteed VGPR residency
        const float4 w0 = wrow[0],  w1 = wrow[1],  w2 = wrow[2],  w3 = wrow[3];
        const float4 w4 = wrow[4],  w5 = wrow[5],  w6 = wrow[6],  w7 = wrow[7];
        const float4 w8 = wrow[8],  w9 = wrow[9],  w10 = wrow[10], w11 = wrow[11];
        const float4 w12 = wrow[12], w13 = wrow[13], w14 = wrow[14], w15 = wrow[15];

        float pd = 0.f, pr0 = 0.f, pr1 = 0.f;
        const float* wih_d = W_ih + j * 256 + p * 64;
        const float* wih_r = W_ih + j * 256 + 128 + p * 64;
#pragma unroll 4
        for (int k = 0; k < 64; ++k) {
            pd  = fmaf(wih_d[k], v_d[p * 64 + k],        pd);
            pr0 = fmaf(wih_r[k], Remb[p * 64 + k],       pr0);
            pr1 = fmaf(wih_r[k], Remb[128 + p * 64 + k], pr1);
        }
        sh[896 + t] = pd; sh[1664 + t] = pr0; sh[2432 + t] = pr1;
        if (t < DD) sh[t] = 0.f;
        if (t < SS) {
            sh[3200 + t]  = D_emb[d_seq[b * SS + t]];
            shi[3300 + t] = r_seq[b * SS + t];
        }
        __syncthreads();

        float gd_r=0,gd_z=0,gd_n=0, g0_r=0,g0_z=0,g0_n=0, g1_r=0,g1_z=0,g1_n=0;
        float bi_r=0,bi_z=0,bi_n=0, bh_r=0,bh_z=0,bh_n=0, h = 0.f;
        if (t < DD) {
            gd_r = sh[896+t]      + sh[896+t+384];
            gd_z = sh[896+t+128]  + sh[896+t+512];
            gd_n = sh[896+t+256]  + sh[896+t+640];
            g0_r = sh[1664+t]     + sh[1664+t+384];
            g0_z = sh[1664+t+128] + sh[1664+t+512];
            g0_n = sh[1664+t+256] + sh[1664+t+640];
            g1_r = sh[2432+t]     + sh[2432+t+384];
            g1_z = sh[2432+t+128] + sh[2432+t+512];
            g1_n = sh[2432+t+256] + sh[2432+t+640];
            bi_r = b_ih[t]; bi_z = b_ih[t+128]; bi_n = b_ih[t+256];
            bh_r = b_hh[t]; bh_z = b_hh[t+128]; bh_n = b_hh[t+256];
        }

        for (int s = 0; s < SS; ++s) {
            float a0 = 0.f, a1 = 0.f, a2 = 0.f, a3 = 0.f;
            const float4* hv4 = reinterpret_cast<const float4*>(sh) + p * 16;
            float4 h0 = hv4[0], h1 = hv4[1], h2 = hv4[2], h3 = hv4[3];
            FMA4(w0, h0); FMA4(w1, h1); FMA4(w2, h2); FMA4(w3, h3);
            h0 = hv4[4]; h1 = hv4[5]; h2 = hv4[6]; h3 = hv4[7];
            FMA4(w4, h0); FMA4(w5, h1); FMA4(w6, h2); FMA4(w7, h3);
            h0 = hv4[8]; h1 = hv4[9]; h2 = hv4[10]; h3 = hv4[11];
            FMA4(w8, h0); FMA4(w9, h1); FMA4(w10, h2); FMA4(w11, h3);
            h0 = hv4[12]; h1 = hv4[13]; h2 = hv4[14]; h3 = hv4[15];
            FMA4(w12, h0); FMA4(w13, h1); FMA4(w14, h2); FMA4(w15, h3);
            sh[128 + t] = (a0 + a1) + (a2 + a3);
            __syncthreads();
            if (t < DD) {
                float ghr = sh[128+t]     + sh[128+t+384] + bh_r;
                float ghz = sh[128+t+128] + sh[128+t+512] + bh_z;
                float ghn = sh[128+t+256] + sh[128+t+640] + bh_n;
                float gamma = sh[3200 + s]; int rr = shi[3300 + s];
                float gir = fmaf(gamma, gd_r, (rr ? g1_r : g0_r) + bi_r);
                float giz = fmaf(gamma, gd_z, (rr ? g1_z : g0_z) + bi_z);
                float gin = fmaf(gamma, gd_n, (rr ? g1_n : g0_n) + bi_n);
                float r = fast_sig(gir + ghr);
                float z = fast_sig(giz + ghz);
                float n = fast_tanh(fmaf(r, ghn, gin));
                h = (1.f - z) * n + z * h;
                sh[t] = h;
                sh[HALL + s * DD + t] = h;   // LDS only; no global op in loop
            }
            __syncthreads();
        }

        // ---- h_out writeback (no barriers needed past this point) ----
        {
            const float4* hsrc = reinterpret_cast<const float4*>(sh + HALL);
            float4* hdst = reinterpret_cast<float4*>(h_out + (size_t)b * SS * DD);
            for (int i = t; i < SS * DD / 4; i += 768) hdst[i] = hsrc[i];
        }

        // ---- fused alpha MLP: wave w handles rows s = w, w+12, ... ----
        {
            const int w = t >> 6, l = t & 63;
            const float b1a = l1b1[l], b1b = l1b1[64 + l];
            const float w2a = l1W2[l], w2b = l1W2[64 + l];
            const float ab  = l1b2[0];
            for (int s = w; s < SS; s += 12) {
                const float* hrow = sh + HALL + s * DD;
                float a0 = b1a, a1 = b1b;
#pragma unroll
                for (int k = 0; k < DD; k += 4) {
                    float4 hv = *reinterpret_cast<const float4*>(hrow + k);       // wave-uniform (broadcast)
                    float4 wa = *reinterpret_cast<const float4*>(&l1W1[l * DD + k]);
                    float4 wb = *reinterpret_cast<const float4*>(&l1W1[(64 + l) * DD + k]);
                    a0 = fmaf(wa.x, hv.x, fmaf(wa.y, hv.y, fmaf(wa.z, hv.z, fmaf(wa.w, hv.w, a0))));
                    a1 = fmaf(wb.x, hv.x, fmaf(wb.y, hv.y, fmaf(wb.z, hv.z, fmaf(wb.w, hv.w, a1))));
                }
                float pp = dpp_sum64(fmaf(fmaxf(a0, 0.f), w2a, fmaxf(a1, 0.f) * w2b));
                if (l == 63) alpha[b * SS + s] = pp + ab;
            }
        }
    } else if (t < 64) {
        // =============== scan role (single wave) ===============
        const int b = blk - BB;
        float* C2s = sh;
        float* C3s = sh + NCC2;
        for (int k = t; k < NCC2 + NC3P; k += 64) sh[k] = 0.f;
        for (int k = t; k < SS; k += 64) {
            shi[2501 + k] = c2_seq[b * SS + k];
            sh[3004 + k]  = D_emb[d_seq[b * SS + k]];
            shi[3104 + k] = r_seq[b * SS + k];
        }
        for (int k = t; k < SS; k += 64)
            reinterpret_cast<int4*>(shi + 2604)[k] = reinterpret_cast<const int4*>(c3_seq + b * SS * TT)[k];

        // reg-resident u-vectors (rank-1 factorization of l2/l3 first layers)
        const float* W2r = l2W1;
        const float* W3r = l3W1;
        const float u2a0 = dot128(W2r + t * 512,             v_c2);
        const float u2a1 = dot128(W2r + (64 + t) * 512,      v_c2);
        const float u2b0 = dot128(W2r + t * 512 + 128,       v_c3);
        const float u2b1 = dot128(W2r + (64 + t) * 512 + 128, v_c3);
        const float u2c0 = dot128(W2r + t * 512 + 256,       v_d);
        const float u2c1 = dot128(W2r + (64 + t) * 512 + 256, v_d);
        const float u2d00 = dot128(W2r + t * 512 + 384,       Remb);
        const float u2d01 = dot128(W2r + (64 + t) * 512 + 384, Remb);
        const float u2d10 = dot128(W2r + t * 512 + 384,       Remb + 128);
        const float u2d11 = dot128(W2r + (64 + t) * 512 + 384, Remb + 128);
        const float u3a0 = dot128(W3r + t * 512,             v_c2);
        const float u3a1 = dot128(W3r + (64 + t) * 512,      v_c2);
        const float u3b0 = dot128(W3r + t * 512 + 128,       v_c3);
        const float u3b1 = dot128(W3r + (64 + t) * 512 + 128, v_c3);
        const float u3c0 = dot128(W3r + t * 512 + 256,       v_d);
        const float u3c1 = dot128(W3r + (64 + t) * 512 + 256, v_d);
        const float u3d00 = dot128(W3r + t * 512 + 384,       Remb);
        const float u3d01 = dot128(W3r + (64 + t) * 512 + 384, Remb);
        const float u3d10 = dot128(W3r + t * 512 + 384,       Remb + 128);
        const float u3d11 = dot128(W3r + (64 + t) * 512 + 384, Remb + 128);
        const float b2_0 = l2b1[t], b2_1 = l2b1[64 + t];
        const float w2_0 = l2W2[t], w2_1 = l2W2[64 + t];
        const float b3_0 = l3b1[t], b3_1 = l3b1[64 + t];
        const float w3_0 = l3W2[t], w3_1 = l3W2[64 + t];
        const float c2bias = l2b2[0], c3bias = l3b2[0];

        // prefetch step-0 scalars
        int  nc2 = shi[2501];
        int4 nc3 = reinterpret_cast<const int4*>(shi + 2604)[0];
        float ngam = sh[3004];
        int   nrr  = shi[3104];

        for (int s = 0; s < SS; ++s) {
            const int rs = b * SS + s;
            const int c2i = nc2;
            const int i0 = nc3.x, i1 = nc3.y, i2 = nc3.z, i3 = nc3.w;
            const float gamma = ngam;
            const int rr = nrr;
            if (s + 1 < SS) {   // prefetch next step's scalars early
                nc2 = shi[2501 + s + 1];
                nc3 = reinterpret_cast<const int4*>(shi + 2604)[s + 1];
                ngam = sh[3004 + s + 1];
                nrr  = shi[3104 + s + 1];
            }

            const float beta2 = C2s[c2i];
            const bool k0 = (i0 != 0), k1 = (i1 != 0), k2 = (i2 != 0), k3 = (i3 != 0);
            const float m0 = k0 ? 1.f : 0.f, m1 = k1 ? 1.f : 0.f;
            const float m2 = k2 ? 1.f : 0.f, m3 = k3 ? 1.f : 0.f;
            const float bt0 = C3s[i0], bt1 = C3s[i1], bt2 = C3s[i2], bt3 = C3s[i3];
            const float msum = m0 + m1 + m2 + m3;
            const float b3bar = (bt0 * m0 + bt1 * m1 + bt2 * m2 + bt3 * m3) * fast_rcp(msum);

            const float ud20 = rr ? u2d10 : u2d00, ud21 = rr ? u2d11 : u2d01;
            const float ud30 = rr ? u3d10 : u3d00, ud31 = rr ? u3d11 : u3d01;

            float h20 = fmaf(beta2, u2a0, fmaf(b3bar, u2b0, fmaf(gamma, u2c0, ud20 + b2_0)));
            float h21 = fmaf(beta2, u2a1, fmaf(b3bar, u2b1, fmaf(gamma, u2c1, ud21 + b2_1)));
            float newc2 = dpp_sum64(fmaf(fmaxf(h20, 0.f), w2_0, fmaxf(h21, 0.f) * w2_1)) + c2bias;

            const float base30 = fmaf(beta2, u3a0, fmaf(gamma, u3c0, ud30 + b3_0));
            const float base31 = fmaf(beta2, u3a1, fmaf(gamma, u3c1, ud31 + b3_1));
            float ha, hb, q0, q1, q2, q3;
            ha = fmaf(bt0, u3b0, base30); hb = fmaf(bt0, u3b1, base31);
            q0 = dpp_sum64(fmaf(fmaxf(ha, 0.f), w3_0, fmaxf(hb, 0.f) * w3_1)) + c3bias;
            ha = fmaf(bt1, u3b0, base30); hb = fmaf(bt1, u3b1, base31);
            q1 = dpp_sum64(fmaf(fmaxf(ha, 0.f), w3_0, fmaxf(hb, 0.f) * w3_1)) + c3bias;
            ha = fmaf(bt2, u3b0, base30); hb = fmaf(bt2, u3b1, base31);
            q2 = dpp_sum64(fmaf(fmaxf(ha, 0.f), w3_0, fmaxf(hb, 0.f) * w3_1)) + c3bias;
            ha = fmaf(bt3, u3b0, base30); hb = fmaf(bt3, u3b1, base31);
            q3 = dpp_sum64(fmaf(fmaxf(ha, 0.f), w3_0, fmaxf(hb, 0.f) * w3_1)) + c3bias;

            // duplicate-aware slot values
            float val0, val1, val2, val3;
            {
                float c = m0 + ((k1 && i1 == i0) ? 1.f : 0.f) + ((k2 && i2 == i0) ? 1.f : 0.f) + ((k3 && i3 == i0) ? 1.f : 0.f);
                float qs = (k0 ? q0 : 0.f) + ((k1 && i1 == i0) ? q1 : 0.f) + ((k2 && i2 == i0) ? q2 : 0.f) + ((k3 && i3 == i0) ? q3 : 0.f);
                val0 = bt0 * (1.f - c) + qs;
            }
            {
                float c = ((k0 && i0 == i1) ? 1.f : 0.f) + m1 + ((k2 && i2 == i1) ? 1.f : 0.f) + ((k3 && i3 == i1) ? 1.f : 0.f);
                float qs = ((k0 && i0 == i1) ? q0 : 0.f) + (k1 ? q1 : 0.f) + ((k2 && i2 == i1) ? q2 : 0.f) + ((k3 && i3 == i1) ? q3 : 0.f);
                val1 = bt1 * (1.f - c) + qs;
            }
            {
                float c = ((k0 && i0 == i2) ? 1.f : 0.f) + ((k1 && i1 == i2) ? 1.f : 0.f) + m2 + ((k3 && i3 == i2) ? 1.f : 0.f);
                float qs = ((k0 && i0 == i2) ? q0 : 0.f) + ((k1 && i1 == i2) ? q1 : 0.f) + (k2 ? q2 : 0.f) + ((k3 && i3 == i2) ? q3 : 0.f);
                val2 = bt2 * (1.f - c) + qs;
            }
            {
                float c = ((k0 && i0 == i3) ? 1.f : 0.f) + ((k1 && i1 == i3) ? 1.f : 0.f) + ((k2 && i2 == i3) ? 1.f : 0.f) + m3;
                float qs = ((k0 && i0 == i3) ? q0 : 0.f) + ((k1 && i1 == i3) ? q1 : 0.f) + ((k2 && i2 == i3) ? q2 : 0.f) + (k3 ? q3 : 0.f);
                val3 = bt3 * (1.f - c) + qs;
            }

            if (t == 63) {
                C2s[c2i] = newc2;
                if (k0) C3s[i0] = val0;
                if (k1) C3s[i1] = val1;
                if (k2) C3s[i2] = val2;
                if (k3) C3s[i3] = val3;
            }

            // fused snapshot store of row (b,s); same-wave DS ordering makes
            // lane63's writes visible to the reads below.
            float* c2row = C2o + (size_t)rs * NCC2;
            float* c3row = C3o + (size_t)rs * NC3P;
            *reinterpret_cast<float4*>(c2row + 4 * t) = *reinterpret_cast<const float4*>(C2s + 4 * t);
            if (t < 61)
                *reinterpret_cast<float4*>(c2row + 256 + 4 * t) = *reinterpret_cast<const float4*>(C2s + 256 + 4 * t);
            const int p0 = (4 - (rs & 3)) & 3;
            if (p0 == 0) {
                // fast path: global row 16B-aligned, C3s base is 16B-aligned
#pragma unroll
                for (int i = 0; i < 8; ++i) {
                    int d4 = i * 64 + t;
                    if (d4 < 500)
                        reinterpret_cast<float4*>(c3row)[d4] = reinterpret_cast<const float4*>(C3s)[d4];
                }
                if (t == 0) c3row[2000] = C3s[2000];
            } else {
                const int tail = (2001 - p0) & 3;
                const int dt = 2001 - tail;
                if (t < p0) c3row[t] = C3s[t];
                if (t < tail) c3row[dt + t] = C3s[dt + t];
#pragma unroll
                for (int i = 0; i < 8; ++i) {
                    int d = p0 + 4 * (i * 64 + t);
                    if (d + 3 <= 2000) {
                        float4 v;
                        v.x = C3s[d]; v.y = C3s[d + 1]; v.z = C3s[d + 2]; v.w = C3s[d + 3];
                        *reinterpret_cast<float4*>(c3row + d) = v;
                    }
                }
            }
        }
    }
}

// ---------------------------------------------------------------------------
extern "C" void kernel_launch(void* const* d_in, const int* in_sizes, int n_in,
                              void* d_out, int out_size, void* d_ws, size_t ws_size,
                              hipStream_t stream)
{
    (void)in_sizes; (void)n_in; (void)out_size; (void)d_ws; (void)ws_size;
    const int*   c2_seq = (const int*)d_in[0];
    const int*   c3_seq = (const int*)d_in[1];
    const int*   d_seq  = (const int*)d_in[2];
    const int*   r_seq  = (const int*)d_in[3];
    const float* D_emb  = (const float*)d_in[4];
    const float* Remb   = (const float*)d_in[5];
    const float* v_c2   = (const float*)d_in[6];
    const float* v_c3   = (const float*)d_in[7];
    const float* v_d    = (const float*)d_in[8];
    const float* W_ih   = (const float*)d_in[9];
    const float* W_hh   = (const float*)d_in[10];
    const float* b_ih   = (const float*)d_in[11];
    const float* b_hh   = (const float*)d_in[12];
    const float* l1W1   = (const float*)d_in[13];
    const float* l1b1   = (const float*)d_in[14];
    const float* l1W2   = (const float*)d_in[15];
    const float* l1b2   = (const float*)d_in[16];
    const float* l2W1   = (const float*)d_in[17];
    const float* l2b1   = (const float*)d_in[18];
    const float* l2W2   = (const float*)d_in[19];
    const float* l2b2   = (const float*)d_in[20];
    const float* l3W1   = (const float*)d_in[21];
    const float* l3b1   = (const float*)d_in[22];
    const float* l3W2   = (const float*)d_in[23];
    const float* l3b2   = (const float*)d_in[24];

    float* out   = (float*)d_out;
    float* alpha = out;                 // [B,S]
    float* h_out = out + 3200;          // [B,S,128]
    float* C2o   = out + 412800;        // [B,S,500]
    float* C3o   = out + 2012800;       // [B,S,2001]

    k_main<<<2 * BB, 768, 0, stream>>>(c2_seq, c3_seq, d_seq, r_seq, D_emb, Remb,
                                       v_c2, v_c3, v_d,
                                       W_ih, W_hh, b_ih, b_hh,
                                       l1W1, l1b1, l1W2, l1b2,
                                       l2W1, l2b1, l2W2, l2b2,
                                       l3W1, l3b1, l3W2, l3b2,
                                       alpha, h_out, C2o, C3o);
}

// Round 4
// 128.966 us; speedup vs baseline: 1.5524x; 1.5524x over previous
//
#include <hip/hip_runtime.h>

#define BB   32
#define SS   100
#define TT   4
#define NCC2 500
#define NC3P 2001
#define DD   128

// LDS float-index layout
//  GRU : h[0..127] | part[128..895] | gam[3200..3299] | rr[3300..3399] | h_all[3456..16255]
//  scan: C2s[0..499] | C3s[500..2500] | tc2[2501..2600] | tc3[2604..3003](16B-aligned) | tgam[3004..3103] | trr[3104..3203]
#define HALL 3456
#define LDSF 16256

__device__ __forceinline__ float fast_rcp(float x) { return __builtin_amdgcn_rcpf(x); }
__device__ __forceinline__ float fast_sig(float x) { return fast_rcp(1.f + __expf(-x)); }
__device__ __forceinline__ float fast_tanh(float x) { return 1.f - 2.f * fast_rcp(__expf(2.f * x) + 1.f); }

// Full 64-lane sum via DPP; result valid in lane 63 only.
__device__ __forceinline__ float dpp_sum64(float x) {
    x += __int_as_float(__builtin_amdgcn_update_dpp(0, __float_as_int(x), 0x111, 0xf, 0xf, true)); // row_shr:1
    x += __int_as_float(__builtin_amdgcn_update_dpp(0, __float_as_int(x), 0x112, 0xf, 0xf, true)); // row_shr:2
    x += __int_as_float(__builtin_amdgcn_update_dpp(0, __float_as_int(x), 0x114, 0xf, 0xf, true)); // row_shr:4
    x += __int_as_float(__builtin_amdgcn_update_dpp(0, __float_as_int(x), 0x118, 0xf, 0xf, true)); // row_shr:8
    x += __int_as_float(__builtin_amdgcn_update_dpp(0, __float_as_int(x), 0x142, 0xa, 0xf, true)); // row_bcast:15
    x += __int_as_float(__builtin_amdgcn_update_dpp(0, __float_as_int(x), 0x143, 0xc, 0xf, true)); // row_bcast:31
    return x;
}

// Sum within each group of 16 lanes; result valid in lane 15 of each group.
__device__ __forceinline__ float dpp_sum16(float x) {
    x += __int_as_float(__builtin_amdgcn_update_dpp(0, __float_as_int(x), 0x111, 0xf, 0xf, true));
    x += __int_as_float(__builtin_amdgcn_update_dpp(0, __float_as_int(x), 0x112, 0xf, 0xf, true));
    x += __int_as_float(__builtin_amdgcn_update_dpp(0, __float_as_int(x), 0x114, 0xf, 0xf, true));
    x += __int_as_float(__builtin_amdgcn_update_dpp(0, __float_as_int(x), 0x118, 0xf, 0xf, true));
    return x;
}

__device__ __forceinline__ float dot4(float4 a, float4 b) {
    return fmaf(a.x, b.x, fmaf(a.y, b.y, fmaf(a.z, b.z, a.w * b.w)));
}

#define FMA4(W, H) do { a0 = fmaf((W).x, (H).x, a0); a1 = fmaf((W).y, (H).y, a1); \
                        a2 = fmaf((W).z, (H).z, a2); a3 = fmaf((W).w, (H).w, a3); } while (0)

// ---------------------------------------------------------------------------
// k_pre: u-vectors for MLP2/MLP3 rank-1 factorization, COALESCED.
// 32 blocks x 64 threads; one wave handles 8 W-rows; lane t covers 8 contiguous
// floats of the row (segment g = t>>4 selects the v-vector); group-of-16 DPP reduce.
// ws layout: u2 at 0 {a,b,c,d0,d1}[128]; u3 at 640.
__global__ __launch_bounds__(64) void k_pre(const float* __restrict__ l2W1,
                                            const float* __restrict__ l3W1,
                                            const float* __restrict__ v_c2,
                                            const float* __restrict__ v_c3,
                                            const float* __restrict__ v_d,
                                            const float* __restrict__ Remb,
                                            float* __restrict__ ws)
{
    const int t = threadIdx.x;
    const int g = t >> 4;
    const int c = (t & 15) * 8;
    const float* vsrc = (g == 0) ? v_c2 : (g == 1) ? v_c3 : (g == 2) ? v_d : Remb;
    const float4 va  = *(const float4*)(vsrc + c);
    const float4 vb  = *(const float4*)(vsrc + c + 4);
    const float4 va1 = *(const float4*)(Remb + 128 + c);
    const float4 vb1 = *(const float4*)(Remb + 132 + c);
#pragma unroll
    for (int r = 0; r < 8; ++r) {
        const int row_id = blockIdx.x * 8 + r;       // 0..255
        const float* W = (row_id < 128) ? l2W1 : l3W1;
        float* U = ws + ((row_id < 128) ? 0 : 640);
        const int i = row_id & 127;
        const float* wr = W + i * 512 + g * 128 + c; // coalesced: lane stride 32B
        const float4 w0 = *(const float4*)(wr);
        const float4 w1 = *(const float4*)(wr + 4);
        float p  = dot4(w0, va)  + dot4(w1, vb);
        float p1 = dot4(w0, va1) + dot4(w1, vb1);
        p  = dpp_sum16(p);
        p1 = dpp_sum16(p1);
        if ((t & 15) == 15) {
            U[g * 128 + i] = p;
            if (g == 3) U[512 + i] = p1;
        }
    }
}

// ---------------------------------------------------------------------------
// blocks 0..31 : GRU (768 thr, k-split x2, W_hh in named VGPRs, LDS-only loop,
//                bulk h_out writeback)
// blocks 32..63: scan (1 wave, barrier-free, u-vectors from ws, DPP reductions,
//                fused snapshot stores)
__global__ __launch_bounds__(768, 1) void k_main(
    const int* __restrict__ c2_seq, const int* __restrict__ c3_seq,
    const int* __restrict__ d_seq,  const int* __restrict__ r_seq,
    const float* __restrict__ D_emb, const float* __restrict__ Remb,
    const float* __restrict__ v_d,
    const float* __restrict__ W_ih, const float* __restrict__ W_hh,
    const float* __restrict__ b_ih, const float* __restrict__ b_hh,
    const float* __restrict__ l2b1, const float* __restrict__ l2W2, const float* __restrict__ l2b2,
    const float* __restrict__ l3b1, const float* __restrict__ l3W2, const float* __restrict__ l3b2,
    const float* __restrict__ ws, float* __restrict__ h_out,
    float* __restrict__ C2o, float* __restrict__ C3o)
{
    __shared__ __align__(16) float sh[LDSF];
    int* shi = (int*)sh;
    const int blk = blockIdx.x;
    const int t = threadIdx.x;

    if (blk < BB) {
        // =============== GRU role ===============
        const int b = blk;
        const int p = (t >= 384) ? 1 : 0;
        const int j = t - p * 384;
        const float4* wrow = reinterpret_cast<const float4*>(W_hh + j * DD + p * 64);
        const float4 w0 = wrow[0],  w1 = wrow[1],  w2 = wrow[2],  w3 = wrow[3];
        const float4 w4 = wrow[4],  w5 = wrow[5],  w6 = wrow[6],  w7 = wrow[7];
        const float4 w8 = wrow[8],  w9 = wrow[9],  w10 = wrow[10], w11 = wrow[11];
        const float4 w12 = wrow[12], w13 = wrow[13], w14 = wrow[14], w15 = wrow[15];

        // input-projection factors, float4 loads (4x fewer scattered requests),
        // wih_r shared between pr0/pr1; v-vector loads are wave-uniform.
        float pd = 0.f, pr0 = 0.f, pr1 = 0.f;
        {
            const float4* wd4 = (const float4*)(W_ih + j * 256 + p * 64);
            const float4* wr4 = (const float4*)(W_ih + j * 256 + 128 + p * 64);
            const float4* vd4 = (const float4*)(v_d + p * 64);
            const float4* r04 = (const float4*)(Remb + p * 64);
            const float4* r14 = (const float4*)(Remb + 128 + p * 64);
#pragma unroll
            for (int k4 = 0; k4 < 16; ++k4) {
                const float4 wd = wd4[k4], wr = wr4[k4];
                const float4 vd = vd4[k4], r0 = r04[k4], r1 = r14[k4];
                pd  = fmaf(wd.x, vd.x, fmaf(wd.y, vd.y, fmaf(wd.z, vd.z, fmaf(wd.w, vd.w, pd))));
                pr0 = fmaf(wr.x, r0.x, fmaf(wr.y, r0.y, fmaf(wr.z, r0.z, fmaf(wr.w, r0.w, pr0))));
                pr1 = fmaf(wr.x, r1.x, fmaf(wr.y, r1.y, fmaf(wr.z, r1.z, fmaf(wr.w, r1.w, pr1))));
            }
        }
        sh[896 + t] = pd; sh[1664 + t] = pr0; sh[2432 + t] = pr1;
        if (t < DD) sh[t] = 0.f;
        if (t < SS) {
            sh[3200 + t]  = D_emb[d_seq[b * SS + t]];
            shi[3300 + t] = r_seq[b * SS + t];
        }
        __syncthreads();

        float gd_r=0,gd_z=0,gd_n=0, g0_r=0,g0_z=0,g0_n=0, g1_r=0,g1_z=0,g1_n=0;
        float bi_r=0,bi_z=0,bi_n=0, bh_r=0,bh_z=0,bh_n=0, h = 0.f;
        if (t < DD) {
            gd_r = sh[896+t]      + sh[896+t+384];
            gd_z = sh[896+t+128]  + sh[896+t+512];
            gd_n = sh[896+t+256]  + sh[896+t+640];
            g0_r = sh[1664+t]     + sh[1664+t+384];
            g0_z = sh[1664+t+128] + sh[1664+t+512];
            g0_n = sh[1664+t+256] + sh[1664+t+640];
            g1_r = sh[2432+t]     + sh[2432+t+384];
            g1_z = sh[2432+t+128] + sh[2432+t+512];
            g1_n = sh[2432+t+256] + sh[2432+t+640];
            bi_r = b_ih[t]; bi_z = b_ih[t+128]; bi_n = b_ih[t+256];
            bh_r = b_hh[t]; bh_z = b_hh[t+128]; bh_n = b_hh[t+256];
        }
        __syncthreads();   // gd reads of presum area complete before loop reuses nothing; keeps phases clean

        for (int s = 0; s < SS; ++s) {
            float a0 = 0.f, a1 = 0.f, a2 = 0.f, a3 = 0.f;
            const float4* hv4 = reinterpret_cast<const float4*>(sh) + p * 16;
            float4 h0 = hv4[0], h1 = hv4[1], h2 = hv4[2], h3 = hv4[3];
            FMA4(w0, h0); FMA4(w1, h1); FMA4(w2, h2); FMA4(w3, h3);
            h0 = hv4[4]; h1 = hv4[5]; h2 = hv4[6]; h3 = hv4[7];
            FMA4(w4, h0); FMA4(w5, h1); FMA4(w6, h2); FMA4(w7, h3);
            h0 = hv4[8]; h1 = hv4[9]; h2 = hv4[10]; h3 = hv4[11];
            FMA4(w8, h0); FMA4(w9, h1); FMA4(w10, h2); FMA4(w11, h3);
            h0 = hv4[12]; h1 = hv4[13]; h2 = hv4[14]; h3 = hv4[15];
            FMA4(w12, h0); FMA4(w13, h1); FMA4(w14, h2); FMA4(w15, h3);
            sh[128 + t] = (a0 + a1) + (a2 + a3);
            __syncthreads();
            if (t < DD) {
                float ghr = sh[128+t]     + sh[128+t+384] + bh_r;
                float ghz = sh[128+t+128] + sh[128+t+512] + bh_z;
                float ghn = sh[128+t+256] + sh[128+t+640] + bh_n;
                float gamma = sh[3200 + s]; int rr = shi[3300 + s];
                float gir = fmaf(gamma, gd_r, (rr ? g1_r : g0_r) + bi_r);
                float giz = fmaf(gamma, gd_z, (rr ? g1_z : g0_z) + bi_z);
                float gin = fmaf(gamma, gd_n, (rr ? g1_n : g0_n) + bi_n);
                float r = fast_sig(gir + ghr);
                float z = fast_sig(giz + ghz);
                float n = fast_tanh(fmaf(r, ghn, gin));
                h = (1.f - z) * n + z * h;
                sh[t] = h;
                sh[HALL + s * DD + t] = h;   // LDS only; no global op in loop
            }
            __syncthreads();
        }

        // bulk h_out writeback
        {
            const float4* hsrc = reinterpret_cast<const float4*>(sh + HALL);
            float4* hdst = reinterpret_cast<float4*>(h_out + (size_t)b * SS * DD);
            for (int i = t; i < SS * DD / 4; i += 768) hdst[i] = hsrc[i];
        }
    } else if (t < 64) {
        // =============== scan role (single wave) ===============
        const int b = blk - BB;
        float* C2s = sh;
        float* C3s = sh + NCC2;
        for (int k = t; k < NCC2 + NC3P; k += 64) sh[k] = 0.f;
        for (int k = t; k < SS; k += 64) {
            shi[2501 + k] = c2_seq[b * SS + k];
            sh[3004 + k]  = D_emb[d_seq[b * SS + k]];
            shi[3104 + k] = r_seq[b * SS + k];
        }
        for (int k = t; k < SS; k += 64)
            reinterpret_cast<int4*>(shi + 2604)[k] = reinterpret_cast<const int4*>(c3_seq + b * SS * TT)[k];

        // u-vectors from ws (coalesced scalar loads)
        const float* u2 = ws;
        const float* u3 = ws + 640;
        const float u2a0 = u2[t],        u2a1 = u2[64 + t];
        const float u2b0 = u2[128 + t],  u2b1 = u2[192 + t];
        const float u2c0 = u2[256 + t],  u2c1 = u2[320 + t];
        const float u2d00 = u2[384 + t], u2d01 = u2[448 + t];
        const float u2d10 = u2[512 + t], u2d11 = u2[576 + t];
        const float u3a0 = u3[t],        u3a1 = u3[64 + t];
        const float u3b0 = u3[128 + t],  u3b1 = u3[192 + t];
        const float u3c0 = u3[256 + t],  u3c1 = u3[320 + t];
        const float u3d00 = u3[384 + t], u3d01 = u3[448 + t];
        const float u3d10 = u3[512 + t], u3d11 = u3[576 + t];
        const float b2_0 = l2b1[t], b2_1 = l2b1[64 + t];
        const float w2_0 = l2W2[t], w2_1 = l2W2[64 + t];
        const float b3_0 = l3b1[t], b3_1 = l3b1[64 + t];
        const float w3_0 = l3W2[t], w3_1 = l3W2[64 + t];
        const float c2bias = l2b2[0], c3bias = l3b2[0];

        int  nc2 = shi[2501];
        int4 nc3 = reinterpret_cast<const int4*>(shi + 2604)[0];
        float ngam = sh[3004];
        int   nrr  = shi[3104];

        for (int s = 0; s < SS; ++s) {
            const int rs = b * SS + s;
            const int c2i = nc2;
            const int i0 = nc3.x, i1 = nc3.y, i2 = nc3.z, i3 = nc3.w;
            const float gamma = ngam;
            const int rr = nrr;
            if (s + 1 < SS) {
                nc2 = shi[2501 + s + 1];
                nc3 = reinterpret_cast<const int4*>(shi + 2604)[s + 1];
                ngam = sh[3004 + s + 1];
                nrr  = shi[3104 + s + 1];
            }

            const float beta2 = C2s[c2i];
            const bool k0 = (i0 != 0), k1 = (i1 != 0), k2 = (i2 != 0), k3 = (i3 != 0);
            const float m0 = k0 ? 1.f : 0.f, m1 = k1 ? 1.f : 0.f;
            const float m2 = k2 ? 1.f : 0.f, m3 = k3 ? 1.f : 0.f;
            const float bt0 = C3s[i0], bt1 = C3s[i1], bt2 = C3s[i2], bt3 = C3s[i3];
            const float msum = m0 + m1 + m2 + m3;
            const float b3bar = (bt0 * m0 + bt1 * m1 + bt2 * m2 + bt3 * m3) * fast_rcp(msum);

            const float ud20 = rr ? u2d10 : u2d00, ud21 = rr ? u2d11 : u2d01;
            const float ud30 = rr ? u3d10 : u3d00, ud31 = rr ? u3d11 : u3d01;

            float h20 = fmaf(beta2, u2a0, fmaf(b3bar, u2b0, fmaf(gamma, u2c0, ud20 + b2_0)));
            float h21 = fmaf(beta2, u2a1, fmaf(b3bar, u2b1, fmaf(gamma, u2c1, ud21 + b2_1)));
            float newc2 = dpp_sum64(fmaf(fmaxf(h20, 0.f), w2_0, fmaxf(h21, 0.f) * w2_1)) + c2bias;

            const float base30 = fmaf(beta2, u3a0, fmaf(gamma, u3c0, ud30 + b3_0));
            const float base31 = fmaf(beta2, u3a1, fmaf(gamma, u3c1, ud31 + b3_1));
            float ha, hb, q0, q1, q2, q3;
            ha = fmaf(bt0, u3b0, base30); hb = fmaf(bt0, u3b1, base31);
            q0 = dpp_sum64(fmaf(fmaxf(ha, 0.f), w3_0, fmaxf(hb, 0.f) * w3_1)) + c3bias;
            ha = fmaf(bt1, u3b0, base30); hb = fmaf(bt1, u3b1, base31);
            q1 = dpp_sum64(fmaf(fmaxf(ha, 0.f), w3_0, fmaxf(hb, 0.f) * w3_1)) + c3bias;
            ha = fmaf(bt2, u3b0, base30); hb = fmaf(bt2, u3b1, base31);
            q2 = dpp_sum64(fmaf(fmaxf(ha, 0.f), w3_0, fmaxf(hb, 0.f) * w3_1)) + c3bias;
            ha = fmaf(bt3, u3b0, base30); hb = fmaf(bt3, u3b1, base31);
            q3 = dpp_sum64(fmaf(fmaxf(ha, 0.f), w3_0, fmaxf(hb, 0.f) * w3_1)) + c3bias;

            float val0, val1, val2, val3;
            {
                float c = m0 + ((k1 && i1 == i0) ? 1.f : 0.f) + ((k2 && i2 == i0) ? 1.f : 0.f) + ((k3 && i3 == i0) ? 1.f : 0.f);
                float qs = (k0 ? q0 : 0.f) + ((k1 && i1 == i0) ? q1 : 0.f) + ((k2 && i2 == i0) ? q2 : 0.f) + ((k3 && i3 == i0) ? q3 : 0.f);
                val0 = bt0 * (1.f - c) + qs;
            }
            {
                float c = ((k0 && i0 == i1) ? 1.f : 0.f) + m1 + ((k2 && i2 == i1) ? 1.f : 0.f) + ((k3 && i3 == i1) ? 1.f : 0.f);
                float qs = ((k0 && i0 == i1) ? q0 : 0.f) + (k1 ? q1 : 0.f) + ((k2 && i2 == i1) ? q2 : 0.f) + ((k3 && i3 == i1) ? q3 : 0.f);
                val1 = bt1 * (1.f - c) + qs;
            }
            {
                float c = ((k0 && i0 == i2) ? 1.f : 0.f) + ((k1 && i1 == i2) ? 1.f : 0.f) + m2 + ((k3 && i3 == i2) ? 1.f : 0.f);
                float qs = ((k0 && i0 == i2) ? q0 : 0.f) + ((k1 && i1 == i2) ? q1 : 0.f) + (k2 ? q2 : 0.f) + ((k3 && i3 == i2) ? q3 : 0.f);
                val2 = bt2 * (1.f - c) + qs;
            }
            {
                float c = ((k0 && i0 == i3) ? 1.f : 0.f) + ((k1 && i1 == i3) ? 1.f : 0.f) + ((k2 && i2 == i3) ? 1.f : 0.f) + m3;
                float qs = ((k0 && i0 == i3) ? q0 : 0.f) + ((k1 && i1 == i3) ? q1 : 0.f) + ((k2 && i2 == i3) ? q2 : 0.f) + (k3 ? q3 : 0.f);
                val3 = bt3 * (1.f - c) + qs;
            }

            if (t == 63) {
                C2s[c2i] = newc2;
                if (k0) C3s[i0] = val0;
                if (k1) C3s[i1] = val1;
                if (k2) C3s[i2] = val2;
                if (k3) C3s[i3] = val3;
            }

            // fused snapshot store of row (b,s)
            float* c2row = C2o + (size_t)rs * NCC2;
            float* c3row = C3o + (size_t)rs * NC3P;
            *reinterpret_cast<float4*>(c2row + 4 * t) = *reinterpret_cast<const float4*>(C2s + 4 * t);
            if (t < 61)
                *reinterpret_cast<float4*>(c2row + 256 + 4 * t) = *reinterpret_cast<const float4*>(C2s + 256 + 4 * t);
            const int p0 = (4 - (rs & 3)) & 3;
            if (p0 == 0) {
#pragma unroll
                for (int i = 0; i < 8; ++i) {
                    int d4 = i * 64 + t;
                    if (d4 < 500)
                        reinterpret_cast<float4*>(c3row)[d4] = reinterpret_cast<const float4*>(C3s)[d4];
                }
                if (t == 0) c3row[2000] = C3s[2000];
            } else {
                const int tail = (2001 - p0) & 3;
                const int dt = 2001 - tail;
                if (t < p0) c3row[t] = C3s[t];
                if (t < tail) c3row[dt + t] = C3s[dt + t];
#pragma unroll
                for (int i = 0; i < 8; ++i) {
                    int d = p0 + 4 * (i * 64 + t);
                    if (d + 3 <= 2000) {
                        float4 v;
                        v.x = C3s[d]; v.y = C3s[d + 1]; v.z = C3s[d + 2]; v.w = C3s[d + 3];
                        *reinterpret_cast<float4*>(c3row + d) = v;
                    }
                }
            }
        }
    }
}

// ---------------------------------------------------------------------------
// k_alpha2: alpha = MLP1(h). 200 blocks x 256 threads, 16 rows per block.
// Thread (ch = t&127, half = t>>7) keeps its W1 slice (64 floats) in registers,
// loaded once per block; per row only broadcast h loads + 64 FMA + LDS combine.
__global__ __launch_bounds__(256) void k_alpha2(const float* __restrict__ h_seq,
                                                const float* __restrict__ W1,
                                                const float* __restrict__ b1,
                                                const float* __restrict__ W2,
                                                const float* __restrict__ b2,
                                                float* __restrict__ alpha)
{
    __shared__ float part[256];
    __shared__ float red[2];
    const int t = threadIdx.x;
    const int ch = t & 127, half = t >> 7;
    const float4* w4 = (const float4*)(W1 + ch * 128 + half * 64);
    float4 w[16];
#pragma unroll
    for (int i = 0; i < 16; ++i) w[i] = w4[i];
    const float b1v = b1[ch];
    const float w2v = W2[ch];
    const float b2v = b2[0];
    const int base = blockIdx.x * 16;
    for (int r = 0; r < 16; ++r) {
        const float* h = h_seq + (size_t)(base + r) * 128 + half * 64;
        float a0 = 0.f, a1 = 0.f, a2 = 0.f, a3 = 0.f;
#pragma unroll
        for (int i = 0; i < 16; ++i) {
            float4 hv = *(const float4*)(h + 4 * i);
            a0 = fmaf(w[i].x, hv.x, a0); a1 = fmaf(w[i].y, hv.y, a1);
            a2 = fmaf(w[i].z, hv.z, a2); a3 = fmaf(w[i].w, hv.w, a3);
        }
        part[t] = (a0 + a1) + (a2 + a3);
        __syncthreads();
        if (t < 128) {
            float v = fmaxf(part[t] + part[t + 128] + b1v, 0.f) * w2v;
            v = dpp_sum64(v);
            if ((t & 63) == 63) red[t >> 6] = v;
        }
        __syncthreads();
        if (t == 0) alpha[base + r] = red[0] + red[1] + b2v;
    }
}

// ---------------------------------------------------------------------------
extern "C" void kernel_launch(void* const* d_in, const int* in_sizes, int n_in,
                              void* d_out, int out_size, void* d_ws, size_t ws_size,
                              hipStream_t stream)
{
    (void)in_sizes; (void)n_in; (void)out_size; (void)ws_size;
    const int*   c2_seq = (const int*)d_in[0];
    const int*   c3_seq = (const int*)d_in[1];
    const int*   d_seq  = (const int*)d_in[2];
    const int*   r_seq  = (const int*)d_in[3];
    const float* D_emb  = (const float*)d_in[4];
    const float* Remb   = (const float*)d_in[5];
    const float* v_c2   = (const float*)d_in[6];
    const float* v_c3   = (const float*)d_in[7];
    const float* v_d    = (const float*)d_in[8];
    const float* W_ih   = (const float*)d_in[9];
    const float* W_hh   = (const float*)d_in[10];
    const float* b_ih   = (const float*)d_in[11];
    const float* b_hh   = (const float*)d_in[12];
    const float* l1W1   = (const float*)d_in[13];
    const float* l1b1   = (const float*)d_in[14];
    const float* l1W2   = (const float*)d_in[15];
    const float* l1b2   = (const float*)d_in[16];
    const float* l2W1   = (const float*)d_in[17];
    const float* l2b1   = (const float*)d_in[18];
    const float* l2W2   = (const float*)d_in[19];
    const float* l2b2   = (const float*)d_in[20];
    const float* l3W1   = (const float*)d_in[21];
    const float* l3b1   = (const float*)d_in[22];
    const float* l3W2   = (const float*)d_in[23];
    const float* l3b2   = (const float*)d_in[24];

    float* out   = (float*)d_out;
    float* alpha = out;                 // [B,S]
    float* h_out = out + 3200;          // [B,S,128]
    float* C2o   = out + 412800;        // [B,S,500]
    float* C3o   = out + 2012800;       // [B,S,2001]
    float* ws    = (float*)d_ws;

    k_pre<<<32, 64, 0, stream>>>(l2W1, l3W1, v_c2, v_c3, v_d, Remb, ws);
    k_main<<<2 * BB, 768, 0, stream>>>(c2_seq, c3_seq, d_seq, r_seq, D_emb, Remb, v_d,
                                       W_ih, W_hh, b_ih, b_hh,
                                       l2b1, l2W2, l2b2, l3b1, l3W2, l3b2,
                                       ws, h_out, C2o, C3o);
    k_alpha2<<<200, 256, 0, stream>>>(h_out, l1W1, l1b1, l1W2, l1b2, alpha);
}